// Round 6
// baseline (1622.329 us; speedup 1.0000x reference)
//
#include <hip/hip_runtime.h>
#include <math.h>

#define B_   2
#define T_   1024
#define D_   1024
#define H_   16
#define DH_  64
#define DFF_ 4096
#define V_   32000
#define NTOK 2046      // B*(T-1)
#define NCH  125       // V_/256 vocab chunks for loss partials

typedef __attribute__((ext_vector_type(8))) short short8;
typedef __attribute__((ext_vector_type(4))) float floatx4;

__device__ __forceinline__ unsigned short f2bf(float x) {
    unsigned int u = __float_as_uint(x);
    unsigned int r = (u + 0x7fffu + ((u >> 16) & 1u)) >> 16;
    return (unsigned short)r;
}

__device__ __forceinline__ float gelu_tanh(float x) {
    float x3 = x * x * x;
    return 0.5f * x * (1.0f + tanhf(0.7978845608028654f * (x + 0.044715f * x3)));
}

// ---------------- weight prep: out[n*K+k] = bf16(W[k*N+n] + 2*(A@Bm)[k,n]) ----------------
__global__ __launch_bounds__(256) void k_prep_w(const float* __restrict__ W,
        const float* __restrict__ A, const float* __restrict__ Bm,
        unsigned short* __restrict__ out, int K, int N, int lora) {
    __shared__ float t[64][65];
    int n0 = blockIdx.x * 64, k0 = blockIdx.y * 64;
    int tid = threadIdx.x;
    int nn = tid & 63, kb = tid >> 6;
    for (int i = 0; i < 16; i++) {
        int kk = kb * 16 + i;
        float v = W[(size_t)(k0 + kk) * N + n0 + nn];
        if (lora) {
            float s = 0.f;
#pragma unroll
            for (int r = 0; r < 8; r++) s += A[(k0 + kk) * 8 + r] * Bm[r * N + n0 + nn];
            v += 2.0f * s;
        }
        t[kk][nn] = v;
    }
    __syncthreads();
    int kk2 = tid & 63, nb = tid >> 6;
    for (int j = 0; j < 16; j++) {
        int nn2 = nb * 16 + j;
        out[(size_t)(n0 + nn2) * K + k0 + kk2] = f2bf(t[kk2][nn2]);
    }
}

// ---------------- fp32 -> bf16 bulk convert ----------------
__global__ void k_f2bf(const float* __restrict__ in, unsigned short* __restrict__ out, int n4) {
    int i = blockIdx.x * 256 + threadIdx.x;
    if (i >= n4) return;
    float4 v = ((const float4*)in)[i];
    ushort4 o;
    o.x = f2bf(v.x); o.y = f2bf(v.y); o.z = f2bf(v.z); o.w = f2bf(v.w);
    ((ushort4*)out)[i] = o;
}

// ---------------- embedding gather ----------------
__global__ void k_embed_gather(const int* __restrict__ ids, const float* __restrict__ embed,
                               float* __restrict__ embeds) {
    int bt = blockIdx.x;
    int d4 = threadIdx.x;
    int id = ids[bt];
    ((float4*)embeds)[(size_t)bt * 256 + d4] = ((const float4*)embed)[(size_t)id * 256 + d4];
}

// ---------------- LayerNorm. If embeds!=null: x = embeds+Wpos (writes hout); else x = in. ----------------
__global__ __launch_bounds__(256) void k_ln(const float* __restrict__ in,
                                            const float* __restrict__ embeds, const float* __restrict__ Wpos,
                                            const float* __restrict__ sc, const float* __restrict__ bi,
                                            float* __restrict__ hout, float* __restrict__ outf,
                                            unsigned short* __restrict__ outbf,
                                            int c0, int range, int strided_bf) {
    int r = blockIdx.x;
    int b = r / range, pos = c0 + r % range;
    size_t rowoff = (size_t)(b * T_ + pos) * D_;
    int tid = threadIdx.x;
    float xv[4];
    if (embeds) {
#pragma unroll
        for (int j = 0; j < 4; j++) {
            int i = tid + j * 256;
            xv[j] = embeds[rowoff + i] + Wpos[(size_t)pos * D_ + i];
            hout[rowoff + i] = xv[j];
        }
    } else {
#pragma unroll
        for (int j = 0; j < 4; j++) xv[j] = in[rowoff + tid + j * 256];
    }
    float s1 = 0.f, s2 = 0.f;
#pragma unroll
    for (int j = 0; j < 4; j++) { s1 += xv[j]; s2 += xv[j] * xv[j]; }
    __shared__ float r1[256], r2[256];
    r1[tid] = s1; r2[tid] = s2; __syncthreads();
    for (int o = 128; o > 0; o >>= 1) {
        if (tid < o) { r1[tid] += r1[tid + o]; r2[tid] += r2[tid + o]; }
        __syncthreads();
    }
    float mean = r1[0] * (1.0f / D_);
    float var = r2[0] * (1.0f / D_) - mean * mean;
    float inv = rsqrtf(var + 1e-5f);
    size_t bfrow = strided_bf ? (size_t)(b * T_ + pos) : (size_t)r;
#pragma unroll
    for (int j = 0; j < 4; j++) {
        int i = tid + j * 256;
        float y = (xv[j] - mean) * inv * sc[i] + bi[i];
        if (outf) outf[rowoff + i] = y;
        outbf[bfrow * D_ + i] = f2bf(y);
    }
}

// ---------------- direct-load MFMA GEMM (no LDS, no barriers, 4-stage reg pipeline) ----------------
// Wave tile 64x64; block = 128x128 (4 waves in quadrants).
// MODE 1: qkv scatter -> bf16 q / k cache / v cache (u2=vcbf)
// MODE 4: qkv scatter -> q / k / v DIRECT into transposed vtc (u2=vtc)
// MODE 2: split-K atomic residual add fp32 (grid.z = ksegs)
// MODE 3: gelu -> bf16
template <int MODE>
__global__ __launch_bounds__(256) void k_dgemm(const unsigned short* __restrict__ Abf,
        const unsigned short* __restrict__ Bt, const float* __restrict__ bias,
        float* __restrict__ o0, unsigned short* __restrict__ u0,
        unsigned short* __restrict__ u1, unsigned short* __restrict__ u2,
        int M, int N, int K, int c0, int range, int ksegs) {
    int tid = threadIdx.x;
    int lane = tid & 63, w = tid >> 6;
    int quad = lane >> 4, l15 = lane & 15;
    int row0 = blockIdx.y * 128 + (w >> 1) * 64;
    int col0 = blockIdx.x * 128 + (w & 1) * 64;
    int kseg = blockIdx.z;
    int Klen = K / ksegs, ksoff = kseg * Klen;

    const unsigned short* ga[4];
    const unsigned short* gb[4];
#pragma unroll
    for (int mi = 0; mi < 4; mi++) {
        int r = row0 + mi * 16 + l15; if (r >= M) r = M - 1;
        ga[mi] = Abf + (size_t)r * K + ksoff + quad * 8;
    }
#pragma unroll
    for (int nj = 0; nj < 4; nj++)
        gb[nj] = Bt + (size_t)(col0 + nj * 16 + l15) * K + ksoff + quad * 8;

    floatx4 acc[4][4];
#pragma unroll
    for (int i = 0; i < 4; i++)
#pragma unroll
        for (int j = 0; j < 4; j++)
#pragma unroll
            for (int k = 0; k < 4; k++) acc[i][j][k] = 0.f;

    int iters = Klen >> 5;          // always a multiple of 4 here (16 or 32)
    short8 abuf[4][4], bbuf[4][4];
#pragma unroll
    for (int s = 0; s < 3; s++) {
#pragma unroll
        for (int mi = 0; mi < 4; mi++) abuf[s][mi] = *(const short8*)(ga[mi] + s * 32);
#pragma unroll
        for (int nj = 0; nj < 4; nj++) bbuf[s][nj] = *(const short8*)(gb[nj] + s * 32);
    }
    for (int it0 = 0; it0 < iters; it0 += 4) {
#pragma unroll
        for (int u = 0; u < 4; u++) {
            int it = it0 + u;
            int sl = (u + 3) & 3;
            if (it + 3 < iters) {
#pragma unroll
                for (int mi = 0; mi < 4; mi++) abuf[sl][mi] = *(const short8*)(ga[mi] + (it + 3) * 32);
#pragma unroll
                for (int nj = 0; nj < 4; nj++) bbuf[sl][nj] = *(const short8*)(gb[nj] + (it + 3) * 32);
            }
#pragma unroll
            for (int mi = 0; mi < 4; mi++)
#pragma unroll
                for (int nj = 0; nj < 4; nj++)
                    acc[mi][nj] = __builtin_amdgcn_mfma_f32_16x16x32_bf16(abuf[u][mi], bbuf[u][nj], acc[mi][nj], 0, 0, 0);
        }
    }

#pragma unroll
    for (int mi = 0; mi < 4; mi++)
#pragma unroll
        for (int reg = 0; reg < 4; reg++) {
            int r = row0 + mi * 16 + quad * 4 + reg;
            if (r >= M) continue;
            int b = r / range, pos = c0 + r % range;
#pragma unroll
            for (int nj = 0; nj < 4; nj++) {
                int n = col0 + nj * 16 + l15;
                if constexpr (MODE == 1 || MODE == 4) {
                    float v = acc[mi][nj][reg] + bias[n];
                    if (n < 1024) u0[(size_t)r * 1024 + n] = f2bf(v);
                    else if (n < 2048) u1[(size_t)(b * T_ + pos) * 1024 + (n - 1024)] = f2bf(v);
                    else {
                        if constexpr (MODE == 1) {
                            u2[(size_t)(b * T_ + pos) * 1024 + (n - 2048)] = f2bf(v);
                        } else {
                            int idx = n - 2048, h = idx >> 6, d = idx & 63;
                            u2[(size_t)((b * 16 + h) * 64 + d) * T_ + pos] = f2bf(v);
                        }
                    }
                } else if constexpr (MODE == 2) {
                    float v = acc[mi][nj][reg] + (kseg == 0 ? bias[n] : 0.f);
                    atomicAdd(&o0[(size_t)(b * T_ + pos) * D_ + n], v);
                } else if constexpr (MODE == 3) {
                    float v = acc[mi][nj][reg] + bias[n];
                    u0[(size_t)r * N + n] = f2bf(gelu_tanh(v));
                }
            }
        }
}

// ---------------- V transpose into global vtc[(b*16+h)*64+d][T] (big passes) ----------------
__global__ __launch_bounds__(256) void k_vtrans(const unsigned short* __restrict__ vcbf,
        unsigned short* __restrict__ vtc, int c0, int range) {
    __shared__ unsigned short ts[64][72];
    int pt = blockIdx.x, h = blockIdx.y, b = blockIdx.z;
    int t = threadIdx.x;
#pragma unroll
    for (int i = 0; i < 2; i++) {
        int idx = t + i * 256;
        int p = idx >> 3, c8 = idx & 7;
        int pos = c0 + pt * 64 + p;
        if (pos < c0 + range) {
            short8 v = *(const short8*)&vcbf[(size_t)(b * T_ + pos) * D_ + h * 64 + c8 * 8];
            *(short8*)&ts[p][c8 * 8] = v;
        }
    }
    __syncthreads();
#pragma unroll
    for (int i = 0; i < 2; i++) {
        int idx = t + i * 256;
        int d = idx >> 3, p8 = idx & 7;
        unsigned short tmp[8];
#pragma unroll
        for (int j = 0; j < 8; j++) tmp[j] = ts[p8 * 8 + j][d];
        int pos0 = c0 + pt * 64 + p8 * 8;
        size_t rb = (size_t)((b * 16 + h) * 64 + d) * T_;
        if (pos0 + 7 < c0 + range) {
            *(short8*)&vtc[rb + pos0] = *(short8*)tmp;
        } else {
            for (int j = 0; j < 8; j++)
                if (pos0 + j < c0 + range) vtc[rb + pos0 + j] = tmp[j];
        }
    }
}

// ---------------- barrier-free MFMA flash attention ----------------
__global__ __launch_bounds__(256) void k_fattn(const unsigned short* __restrict__ qbf,
        const unsigned short* __restrict__ kcbf, const unsigned short* __restrict__ vtc,
        unsigned short* __restrict__ ctxbf, int c0, int range) {
    __shared__ unsigned short pw[4][16][72];
    int tid = threadIdx.x;
    int w = tid >> 6, lane = tid & 63, quad = lane >> 4, l15 = lane & 15;
    int qt = blockIdx.x, h = blockIdx.y, b = blockIdx.z;
    int q0 = qt * 64 + w * 16;
    if (q0 >= range) return;                 // no barriers in this kernel -> safe
    int qtop = q0 + 15; if (qtop >= range) qtop = range - 1;
    int nkt = (c0 + qtop) / 64 + 1;

    int qrow = q0 + l15; if (qrow >= range) qrow = range - 1;
    const unsigned short* qp = qbf + (size_t)(b * range + qrow) * D_ + h * 64 + quad * 8;
    short8 aq0 = *(const short8*)qp;
    short8 aq1 = *(const short8*)(qp + 32);

    floatx4 oacc[4];
#pragma unroll
    for (int dg = 0; dg < 4; dg++)
#pragma unroll
        for (int r = 0; r < 4; r++) oacc[dg][r] = 0.f;
    float m_r[4] = {-1e30f, -1e30f, -1e30f, -1e30f};
    float l_r[4] = {0.f, 0.f, 0.f, 0.f};

    const unsigned short* kb_p = kcbf + (size_t)b * T_ * D_ + h * 64 + quad * 8;
    const unsigned short* vb_p = vtc + (size_t)((b * 16 + h) * 64 + l15) * T_ + quad * 8;

    for (int kt = 0; kt < nkt; kt++) {
        int kb = kt * 64;
        floatx4 s[4];
#pragma unroll
        for (int g = 0; g < 4; g++) {
            const unsigned short* kp = kb_p + (size_t)(kb + g * 16 + l15) * D_;
            short8 bk0 = *(const short8*)kp;
            short8 bk1 = *(const short8*)(kp + 32);
            floatx4 z; z[0] = 0.f; z[1] = 0.f; z[2] = 0.f; z[3] = 0.f;
            z = __builtin_amdgcn_mfma_f32_16x16x32_bf16(aq0, bk0, z, 0, 0, 0);
            s[g] = __builtin_amdgcn_mfma_f32_16x16x32_bf16(aq1, bk1, z, 0, 0, 0);
        }
#pragma unroll
        for (int r = 0; r < 4; r++) {
            int qpos = c0 + q0 + quad * 4 + r;
            float mx = -1e30f;
#pragma unroll
            for (int g = 0; g < 4; g++) {
                int kpos = kb + g * 16 + l15;
                float sv = (kpos <= qpos) ? s[g][r] * 0.125f : -1e30f;
                s[g][r] = sv; mx = fmaxf(mx, sv);
            }
            mx = fmaxf(mx, __shfl_xor(mx, 1));
            mx = fmaxf(mx, __shfl_xor(mx, 2));
            mx = fmaxf(mx, __shfl_xor(mx, 4));
            mx = fmaxf(mx, __shfl_xor(mx, 8));
            float mn = fmaxf(m_r[r], mx);
            float alpha = __expf(m_r[r] - mn);
            m_r[r] = mn;
            float ls = 0.f;
#pragma unroll
            for (int g = 0; g < 4; g++) {
                float p = __expf(s[g][r] - mn);
                s[g][r] = p; ls += p;
            }
            ls += __shfl_xor(ls, 1);
            ls += __shfl_xor(ls, 2);
            ls += __shfl_xor(ls, 4);
            ls += __shfl_xor(ls, 8);
            l_r[r] = l_r[r] * alpha + ls;
#pragma unroll
            for (int dg = 0; dg < 4; dg++) oacc[dg][r] *= alpha;
        }
#pragma unroll
        for (int g = 0; g < 4; g++)
#pragma unroll
            for (int r = 0; r < 4; r++)
                pw[w][quad * 4 + r][g * 16 + l15] = f2bf(s[g][r]);
        short8 ap0 = *(const short8*)&pw[w][l15][quad * 8];
        short8 ap1 = *(const short8*)&pw[w][l15][32 + quad * 8];
#pragma unroll
        for (int dg = 0; dg < 4; dg++) {
            const unsigned short* vp = vb_p + (size_t)(dg * 16) * T_ + kb;
            short8 bv0 = *(const short8*)vp;
            short8 bv1 = *(const short8*)(vp + 32);
            oacc[dg] = __builtin_amdgcn_mfma_f32_16x16x32_bf16(ap0, bv0, oacc[dg], 0, 0, 0);
            oacc[dg] = __builtin_amdgcn_mfma_f32_16x16x32_bf16(ap1, bv1, oacc[dg], 0, 0, 0);
        }
    }
#pragma unroll
    for (int dg = 0; dg < 4; dg++)
#pragma unroll
        for (int r = 0; r < 4; r++) {
            int qloc = q0 + quad * 4 + r;
            if (qloc < range)
                ctxbf[(size_t)(b * range + qloc) * D_ + h * 64 + dg * 16 + l15] =
                    f2bf(oacc[dg][r] / l_r[r]);
        }
}

// ---------------- latent vec fills ----------------
__global__ void k_latent0(const float* __restrict__ hid, const float* __restrict__ lw,
                          float* __restrict__ embeds) {
    int idx = blockIdx.x * 256 + threadIdx.x;
    if (idx >= B_ * D_) return;
    int b = idx / D_, d = idx % D_;
    float w0 = lw[0], w1 = lw[1], w2 = lw[2];
    float mx = fmaxf(w0, fmaxf(w1, w2));
    float e0 = __expf(w0 - mx), e1 = __expf(w1 - mx), e2 = __expf(w2 - mx);
    float inv = 1.0f / (e0 + e1 + e2);
    float v = (e0 * hid[(size_t)(b * T_ + 509) * D_ + d] +
               e1 * hid[(size_t)(b * T_ + 510) * D_ + d] +
               e2 * hid[(size_t)(b * T_ + 511) * D_ + d]) * inv;
    embeds[(size_t)(b * T_ + 512) * D_ + d] = v;
}

__global__ void k_latent1(const float* __restrict__ hid, float* __restrict__ embeds, int tok) {
    int idx = blockIdx.x * 256 + threadIdx.x;
    if (idx >= B_ * D_) return;
    int b = idx / D_, d = idx % D_;
    embeds[(size_t)(b * T_ + tok) * D_ + d] = hid[(size_t)(b * T_ + tok - 1) * D_ + d];
}

// ---------------- loss: direct-load MFMA logits + fused (max,sumexp,label) ----------------
// Block = 64 tokens x 256 vocab; 4 waves each 64x64 (same rows, different cols).
// grid (32 rowtiles, 125 chunks). No LDS staging; distance-1 register prefetch.
__global__ __launch_bounds__(256) void k_loss1d(const unsigned short* __restrict__ hidbf,
        const unsigned short* __restrict__ embedbf, const int* __restrict__ labels,
        float* __restrict__ partm, float* __restrict__ parts, float* __restrict__ llogit) {
    __shared__ int lds_lab[64];
    __shared__ float lds_pm[64][4];
    __shared__ float lds_ps[64][4];
    int tid = threadIdx.x;
    int lane = tid & 63, w = tid >> 6;
    int quad = lane >> 4, l15 = lane & 15;
    int chunk = blockIdx.y;
    int row0 = blockIdx.x * 64;
    int col0 = chunk * 256 + w * 64;

    if (tid < 64) {
        int tok = row0 + tid;
        lds_lab[tid] = (tok < NTOK) ? labels[tok + 1 + (tok >= 1023)] : -1;
    }

    const unsigned short* ga[4];
    const unsigned short* gb[4];
#pragma unroll
    for (int mi = 0; mi < 4; mi++) {
        int r = row0 + mi * 16 + l15; if (r >= NTOK) r = NTOK - 1;
        ga[mi] = hidbf + (size_t)(r + (r >= 1023)) * D_ + quad * 8;
    }
#pragma unroll
    for (int nj = 0; nj < 4; nj++)
        gb[nj] = embedbf + (size_t)(col0 + nj * 16 + l15) * D_ + quad * 8;

    floatx4 acc[4][4];
#pragma unroll
    for (int i = 0; i < 4; i++)
#pragma unroll
        for (int j = 0; j < 4; j++)
#pragma unroll
            for (int k = 0; k < 4; k++) acc[i][j][k] = 0.f;

    short8 a0[4], b0[4], a1[4], b1[4];
#pragma unroll
    for (int mi = 0; mi < 4; mi++) a0[mi] = *(const short8*)ga[mi];
#pragma unroll
    for (int nj = 0; nj < 4; nj++) b0[nj] = *(const short8*)gb[nj];
    for (int it = 0; it < 32; it += 2) {
        if (it + 1 < 32) {
#pragma unroll
            for (int mi = 0; mi < 4; mi++) a1[mi] = *(const short8*)(ga[mi] + (it + 1) * 32);
#pragma unroll
            for (int nj = 0; nj < 4; nj++) b1[nj] = *(const short8*)(gb[nj] + (it + 1) * 32);
        }
#pragma unroll
        for (int mi = 0; mi < 4; mi++)
#pragma unroll
            for (int nj = 0; nj < 4; nj++)
                acc[mi][nj] = __builtin_amdgcn_mfma_f32_16x16x32_bf16(a0[mi], b0[nj], acc[mi][nj], 0, 0, 0);
        if (it + 2 < 32) {
#pragma unroll
            for (int mi = 0; mi < 4; mi++) a0[mi] = *(const short8*)(ga[mi] + (it + 2) * 32);
#pragma unroll
            for (int nj = 0; nj < 4; nj++) b0[nj] = *(const short8*)(gb[nj] + (it + 2) * 32);
        }
#pragma unroll
        for (int mi = 0; mi < 4; mi++)
#pragma unroll
            for (int nj = 0; nj < 4; nj++)
                acc[mi][nj] = __builtin_amdgcn_mfma_f32_16x16x32_bf16(a1[mi], b1[nj], acc[mi][nj], 0, 0, 0);
    }
    __syncthreads();   // lds_lab visibility

#pragma unroll
    for (int mi = 0; mi < 4; mi++)
#pragma unroll
        for (int reg = 0; reg < 4; reg++) {
            int rloc = mi * 16 + quad * 4 + reg;
            int lab = lds_lab[rloc];
            float vm = -1e30f;
#pragma unroll
            for (int nj = 0; nj < 4; nj++) {
                float v = acc[mi][nj][reg];
                int vcol = col0 + nj * 16 + l15;
                if (vcol == lab) llogit[row0 + rloc] = v;
                vm = fmaxf(vm, v);
            }
            for (int off = 1; off < 16; off <<= 1) vm = fmaxf(vm, __shfl_xor(vm, off));
            float ss = 0.f;
#pragma unroll
            for (int nj = 0; nj < 4; nj++) ss += __expf(acc[mi][nj][reg] - vm);
            for (int off = 1; off < 16; off <<= 1) ss += __shfl_xor(ss, off);
            if (l15 == 0) { lds_pm[rloc][w] = vm; lds_ps[rloc][w] = ss; }
        }
    __syncthreads();
    if (tid < 64) {
        int tok = row0 + tid;
        if (tok < NTOK) {
            float M = fmaxf(fmaxf(lds_pm[tid][0], lds_pm[tid][1]),
                            fmaxf(lds_pm[tid][2], lds_pm[tid][3]));
            float S = 0.f;
#pragma unroll
            for (int j = 0; j < 4; j++) S += lds_ps[tid][j] * __expf(lds_pm[tid][j] - M);
            partm[(size_t)chunk * NTOK + tok] = M;
            parts[(size_t)chunk * NTOK + tok] = S;
        }
    }
}

// ---------------- loss combine ----------------
__global__ void k_loss2a(const float* __restrict__ partm, const float* __restrict__ parts,
                         const float* __restrict__ ll, float* __restrict__ nll) {
    int tok = blockIdx.x * 256 + threadIdx.x;
    if (tok >= NTOK) return;
    float M = -1e30f;
    for (int c = 0; c < NCH; c++) M = fmaxf(M, partm[(size_t)c * NTOK + tok]);
    float S = 0.f;
    for (int c = 0; c < NCH; c++)
        S += parts[(size_t)c * NTOK + tok] * __expf(partm[(size_t)c * NTOK + tok] - M);
    nll[tok] = logf(S) + M - ll[tok];
}

__global__ __launch_bounds__(256) void k_loss2b(const float* __restrict__ nll, float* __restrict__ out) {
    __shared__ float red[256];
    int tid = threadIdx.x;
    float s = 0.f;
    for (int i = tid; i < NTOK; i += 256) s += nll[i];
    red[tid] = s; __syncthreads();
    for (int o = 128; o > 0; o >>= 1) {
        if (tid < o) red[tid] += red[tid + o];
        __syncthreads();
    }
    if (tid == 0) out[0] = red[0] / (float)NTOK;
}

// ---------------- host ----------------
extern "C" void kernel_launch(void* const* d_in, const int* in_sizes, int n_in,
                              void* d_out, int out_size, void* d_ws, size_t ws_size,
                              hipStream_t stream) {
    const int*   input_ids = (const int*)d_in[0];
    const int*   labels    = (const int*)d_in[2];
    const float* embed     = (const float*)d_in[4];
    const float* Wpos      = (const float*)d_in[5];
    const float* Wqkv      = (const float*)d_in[6];
    const float* bqkv      = (const float*)d_in[7];
    const float* Aq        = (const float*)d_in[8];
    const float* Bq        = (const float*)d_in[9];
    const float* Wo        = (const float*)d_in[10];
    const float* bo        = (const float*)d_in[11];
    const float* Ao        = (const float*)d_in[12];
    const float* Bo        = (const float*)d_in[13];
    const float* W1        = (const float*)d_in[14];
    const float* b1        = (const float*)d_in[15];
    const float* W2        = (const float*)d_in[16];
    const float* b2        = (const float*)d_in[17];
    const float* ln1_s     = (const float*)d_in[18];
    const float* ln1_b     = (const float*)d_in[19];
    const float* ln2_s     = (const float*)d_in[20];
    const float* ln2_b     = (const float*)d_in[21];
    const float* lnf_s     = (const float*)d_in[22];
    const float* lnf_b     = (const float*)d_in[23];
    const float* latent_w  = (const float*)d_in[24];

    char* base = (char*)d_ws;
    size_t off = 0;
    auto alloc = [&](size_t bytes) { void* p = base + off; off += (bytes + 255) & ~255ULL; return p; };

    float* embeds  = (float*)alloc((size_t)B_ * T_ * D_ * 4);
    float* hbuf    = (float*)alloc((size_t)B_ * T_ * D_ * 4);
    float* hidbuf  = (float*)alloc((size_t)B_ * T_ * D_ * 4);
    float* partm   = (float*)alloc((size_t)NCH * NTOK * 4);
    float* parts_  = (float*)alloc((size_t)NCH * NTOK * 4);
    float* llogit  = (float*)alloc((size_t)NTOK * 4);
    float* nllbuf  = (float*)alloc((size_t)NTOK * 4);
    unsigned short* wqkvT  = (unsigned short*)alloc((size_t)3072 * 1024 * 2);
    unsigned short* woT    = (unsigned short*)alloc((size_t)1024 * 1024 * 2);
    unsigned short* W1T    = (unsigned short*)alloc((size_t)4096 * 1024 * 2);
    unsigned short* W2T    = (unsigned short*)alloc((size_t)1024 * 4096 * 2);
    unsigned short* embedbf = (unsigned short*)alloc((size_t)V_ * D_ * 2);
    unsigned short* hidbf  = (unsigned short*)alloc((size_t)B_ * T_ * D_ * 2);
    unsigned short* abf    = (unsigned short*)alloc((size_t)1024 * D_ * 2);
    unsigned short* ctxbf  = (unsigned short*)alloc((size_t)1024 * D_ * 2);
    unsigned short* ffbw   = (unsigned short*)alloc((size_t)1024 * DFF_ * 2);
    unsigned short* qbf    = (unsigned short*)alloc((size_t)1024 * D_ * 2);
    unsigned short* kcbf   = (unsigned short*)alloc((size_t)B_ * T_ * D_ * 2);
    unsigned short* vcbf   = (unsigned short*)alloc((size_t)B_ * T_ * D_ * 2);
    unsigned short* vtc    = (unsigned short*)alloc((size_t)B_ * H_ * DH_ * T_ * 2);

    // weight prep (transpose + LoRA merge + bf16)
    k_prep_w<<<dim3(3072 / 64, 1024 / 64), 256, 0, stream>>>(Wqkv, Aq, Bq, wqkvT, 1024, 3072, 1);
    k_prep_w<<<dim3(1024 / 64, 1024 / 64), 256, 0, stream>>>(Wo, Ao, Bo, woT, 1024, 1024, 1);
    k_prep_w<<<dim3(4096 / 64, 1024 / 64), 256, 0, stream>>>(W1, nullptr, nullptr, W1T, 1024, 4096, 0);
    k_prep_w<<<dim3(1024 / 64, 4096 / 64), 256, 0, stream>>>(W2, nullptr, nullptr, W2T, 4096, 1024, 0);
    k_f2bf<<<(V_ * D_ / 4 + 255) / 256, 256, 0, stream>>>(embed, embedbf, V_ * D_ / 4);
    k_embed_gather<<<B_ * T_, 256, 0, stream>>>(input_ids, embed, embeds);

    auto run_pass = [&](int c0, int c1) {
        int range = c1 - c0;
        int Mr = B_ * range;
        int gy = (Mr + 127) / 128;
        int qt = (range + 63) / 64;
        // ln1 (fused h = embeds + Wpos -> hbuf)
        k_ln<<<Mr, 256, 0, stream>>>(nullptr, embeds, Wpos, ln1_s, ln1_b, hbuf, nullptr, abf, c0, range, 0);
        if (range == 1) {
            k_dgemm<4><<<dim3(3072 / 128, gy), 256, 0, stream>>>(abf, wqkvT, bqkv, nullptr, qbf, kcbf, vtc,
                                                                 Mr, 3072, 1024, c0, range, 1);
        } else {
            k_dgemm<1><<<dim3(3072 / 128, gy), 256, 0, stream>>>(abf, wqkvT, bqkv, nullptr, qbf, kcbf, vcbf,
                                                                 Mr, 3072, 1024, c0, range, 1);
            k_vtrans<<<dim3(qt, H_, B_), 256, 0, stream>>>(vcbf, vtc, c0, range);
        }
        k_fattn<<<dim3(qt, H_, B_), 256, 0, stream>>>(qbf, kcbf, vtc, ctxbf, c0, range);
        k_dgemm<2><<<dim3(1024 / 128, gy, 2), 256, 0, stream>>>(ctxbf, woT, bo, hbuf, nullptr, nullptr, nullptr,
                                                                Mr, 1024, 1024, c0, range, 2);
        k_ln<<<Mr, 256, 0, stream>>>(hbuf, nullptr, nullptr, ln2_s, ln2_b, nullptr, nullptr, abf, c0, range, 0);
        k_dgemm<3><<<dim3(4096 / 128, gy), 256, 0, stream>>>(abf, W1T, b1, nullptr, ffbw, nullptr, nullptr,
                                                             Mr, 4096, 1024, c0, range, 1);
        k_dgemm<2><<<dim3(1024 / 128, gy, 4), 256, 0, stream>>>(ffbw, W2T, b2, hbuf, nullptr, nullptr, nullptr,
                                                                Mr, 1024, 4096, c0, range, 4);
        k_ln<<<Mr, 256, 0, stream>>>(hbuf, nullptr, nullptr, lnf_s, lnf_b, nullptr, hidbuf, hidbf, c0, range, 1);
    };

    run_pass(0, 512);
    k_latent0<<<(B_ * D_ + 255) / 256, 256, 0, stream>>>(hidbuf, latent_w, embeds);
    run_pass(512, 513);
    k_latent1<<<(B_ * D_ + 255) / 256, 256, 0, stream>>>(hidbuf, embeds, 513);
    run_pass(513, 514);
    k_latent1<<<(B_ * D_ + 255) / 256, 256, 0, stream>>>(hidbuf, embeds, 514);
    run_pass(514, 515);
    k_latent1<<<(B_ * D_ + 255) / 256, 256, 0, stream>>>(hidbuf, embeds, 515);
    run_pass(515, 1024);

    // loss: blocks of 64 tokens x 256 vocab; x = rowtiles for B-slice sharing in L2
    k_loss1d<<<dim3((NTOK + 63) / 64, NCH), 256, 0, stream>>>(hidbf, embedbf, labels, partm, parts_, llogit);
    k_loss2a<<<(NTOK + 255) / 256, 256, 0, stream>>>(partm, parts_, llogit, nllbuf);
    k_loss2b<<<1, 256, 0, stream>>>(nllbuf, (float*)d_out);
}